// Round 2
// baseline (1615.092 us; speedup 1.0000x reference)
//
#include <hip/hip_runtime.h>
#include <cstdint>

#define TP 22528            // 256*88  (t,p) plane size
#define MROWS 90112         // 4*256*88

// ---------------------------------------------------------------------------
// GEMM: C[m, n0+n] = bias[n] + sum_k A[m,k] * W[n,k]
// A: M x K row-major (lda) unless XVIEW (then A = x tensor (4,256,256,88) and
// A[m,k] = x[b, k, t, p] with m=(b*256+t)*88+p -> addr (b*256+k)*TP + (m%TP)).
// W is N x K row-major. Column split: blocks with n0>=splitN use W1/b1a/b1b.
// ---------------------------------------------------------------------------
template<int XVIEW>
__launch_bounds__(256)
__global__ void gemm_k(const float* __restrict__ A, int lda,
                       const float* __restrict__ W0, const float* __restrict__ W1,
                       const float* __restrict__ b0a, const float* __restrict__ b0b,
                       const float* __restrict__ b1a, const float* __restrict__ b1b,
                       float* __restrict__ C, int ldc, int K, int splitN)
{
    __shared__ float As[32][68];
    __shared__ float Bs[32][68];
    const int tid = threadIdx.x;
    const int n0 = blockIdx.x * 64;
    const int m0 = blockIdx.y * 64;
    const float* W; const float* ba; const float* bb; int nr0;
    if (n0 < splitN) { W = W0; ba = b0a; bb = b0b; nr0 = n0; }
    else             { W = W1; ba = b1a; bb = b1b; nr0 = n0 - splitN; }
    const int tx = tid & 15, ty = tid >> 4;
    const int sm = tid >> 3, sk4 = tid & 7;   // staging map (row-major A / W)
    const int xm = tid & 31, xk = tid >> 5;   // staging map (XVIEW)
    float acc[4][4] = {};
    for (int k0 = 0; k0 < K; k0 += 32) {
        if (XVIEW) {
            #pragma unroll
            for (int jm = 0; jm < 64; jm += 32) {
                int m = m0 + xm + jm;
                int bq = m / TP; int rt = m - bq * TP;
                const float* src = A + (size_t)(bq * 256) * TP + rt;
                #pragma unroll
                for (int jk = 0; jk < 32; jk += 8) {
                    int k = k0 + xk + jk;
                    As[xk + jk][xm + jm] = src[(size_t)k * TP];
                }
            }
        } else {
            #pragma unroll
            for (int jm = 0; jm < 64; jm += 32) {
                int m = m0 + sm + jm;
                const float4 av = *(const float4*)(A + (size_t)m * lda + k0 + sk4 * 4);
                As[sk4*4+0][sm+jm] = av.x;
                As[sk4*4+1][sm+jm] = av.y;
                As[sk4*4+2][sm+jm] = av.z;
                As[sk4*4+3][sm+jm] = av.w;
            }
        }
        #pragma unroll
        for (int jn = 0; jn < 64; jn += 32) {
            const float4 wv = *(const float4*)(W + (size_t)(nr0 + sm + jn) * K + k0 + sk4 * 4);
            Bs[sk4*4+0][sm+jn] = wv.x;
            Bs[sk4*4+1][sm+jn] = wv.y;
            Bs[sk4*4+2][sm+jn] = wv.z;
            Bs[sk4*4+3][sm+jn] = wv.w;
        }
        __syncthreads();
        #pragma unroll
        for (int kk = 0; kk < 32; ++kk) {
            const float4 a4 = *(const float4*)&As[kk][ty*4];
            const float4 b4 = *(const float4*)&Bs[kk][tx*4];
            const float a[4] = {a4.x, a4.y, a4.z, a4.w};
            const float b[4] = {b4.x, b4.y, b4.z, b4.w};
            #pragma unroll
            for (int i = 0; i < 4; ++i)
                #pragma unroll
                for (int j = 0; j < 4; ++j)
                    acc[i][j] += a[i] * b[j];
        }
        __syncthreads();
    }
    #pragma unroll
    for (int j = 0; j < 4; ++j) {
        int nl = nr0 + tx*4 + j;
        float bias = ba[nl] + (bb ? bb[nl] : 0.0f);
        #pragma unroll
        for (int i = 0; i < 4; ++i) {
            int m = m0 + ty*4 + i;
            C[(size_t)m * ldc + (n0 + tx*4 + j)] = acc[i][j] + bias;
        }
    }
}

// ---------------------------------------------------------------------------
// LSTM recurrence. One block per (sequence row n, direction).
// XI: [MROWS][512] precomputed x@W_ih^T + b_ih + b_hh; fwd gates cols 0..255,
// bwd gates cols 256..511. H out: [MROWS][128], fwd cols 0..63, bwd 64..127.
// thread j in [0,256) owns gate j; threads 0..63 also own (c,h) of unit j.
// Gate order (jnp.split): i | f | g | o.
// ---------------------------------------------------------------------------
__launch_bounds__(256)
__global__ void lstm_kernel(const float* __restrict__ XI,
                            const float* __restrict__ whh_f,
                            const float* __restrict__ whh_b,
                            float* __restrict__ H)
{
    const int bid = blockIdx.x;      // 0..703
    const int dir = bid & 1;
    const int n   = bid >> 1;        // 0..351
    const int b   = n / 88, p = n - 88 * (n / 88);
    const int j   = threadIdx.x;
    const float* whh = dir ? whh_b : whh_f;
    const int j0 = dir ? 256 : 0;
    const int ho = dir ? 64 : 0;
    float w[64];
    #pragma unroll
    for (int k = 0; k < 64; k += 4) {
        const float4 wv = *(const float4*)(whh + (size_t)j * 64 + k);
        w[k] = wv.x; w[k+1] = wv.y; w[k+2] = wv.z; w[k+3] = wv.w;
    }
    __shared__ float h_sh[64];
    __shared__ float acts[256];
    if (j < 64) h_sh[j] = 0.0f;
    float c = 0.0f;
    __syncthreads();
    const size_t rowbase = (size_t)(b * 256) * 88 + p;
    for (int step = 0; step < 256; ++step) {
        const int t = dir ? (255 - step) : step;
        const size_t r = rowbase + (size_t)t * 88;
        float g = XI[r * 512 + j0 + j];
        #pragma unroll
        for (int k = 0; k < 64; k += 4) {
            const float4 h4 = *(const float4*)&h_sh[k];
            g += h4.x * w[k] + h4.y * w[k+1] + h4.z * w[k+2] + h4.w * w[k+3];
        }
        float a;
        if (j >= 128 && j < 192) {            // g-gate: tanh (wave-uniform branch)
            float e = __expf(2.0f * g);
            a = 1.0f - 2.0f / (e + 1.0f);
        } else {                              // i,f,o: sigmoid
            a = 1.0f / (1.0f + __expf(-g));
        }
        acts[j] = a;
        __syncthreads();
        if (j < 64) {
            float ai = acts[j], af = acts[64 + j], ag = acts[128 + j], ao = acts[192 + j];
            c = af * c + ai * ag;
            float e = __expf(2.0f * c);
            float th = 1.0f - 2.0f / (e + 1.0f);
            float h = ao * th;
            h_sh[j] = h;
            H[r * 128 + ho + j] = h;
        }
        __syncthreads();
    }
}

// ---------------------------------------------------------------------------
// NA1D over t, kernel=7, heads=1. One wave per query row.
// QKV: [MROWS][384] (q|k|v), rows in (b,t,p) order. OUT: [MROWS][128].
// ---------------------------------------------------------------------------
__launch_bounds__(256)
__global__ void na_t_kernel(const float* __restrict__ QKV,
                            const float* __restrict__ rpb,
                            float* __restrict__ OUT)
{
    const int wave = threadIdx.x >> 6;
    const int lane = threadIdx.x & 63;
    const int q = blockIdx.x * 4 + wave;          // row index r = (b*256+i)*88+p
    const int b = q / TP; int rem = q - b * TP;
    const int i = rem / 88; const int p = rem - 88 * (rem / 88);
    int start = i - 3; if (start < 0) start = 0; if (start > 249) start = 249;
    const float scale = 0.08838834764831845f;     // 128^-0.5
    const float* qrow = QKV + (size_t)q * 384;
    const float q0 = qrow[lane] * scale;
    const float q1 = qrow[lane + 64] * scale;
    const size_t rbase = (size_t)(b * 256) * 88 + p;
    float s[7];
    #pragma unroll
    for (int jj = 0; jj < 7; ++jj) {
        const int t = start + jj;
        const float* krow = QKV + (rbase + (size_t)t * 88) * 384 + 128;
        float part = q0 * krow[lane] + q1 * krow[lane + 64];
        part += __shfl_xor(part, 1);
        part += __shfl_xor(part, 2);
        part += __shfl_xor(part, 4);
        part += __shfl_xor(part, 8);
        part += __shfl_xor(part, 16);
        part += __shfl_xor(part, 32);
        int rel = t - i + 6; if (rel < 0) rel = 0; if (rel > 12) rel = 12;
        s[jj] = part + rpb[rel];
    }
    float m = s[0];
    #pragma unroll
    for (int jj = 1; jj < 7; ++jj) m = fmaxf(m, s[jj]);
    float sum = 0.0f;
    #pragma unroll
    for (int jj = 0; jj < 7; ++jj) { s[jj] = __expf(s[jj] - m); sum += s[jj]; }
    const float inv = 1.0f / sum;
    float o0 = 0.0f, o1 = 0.0f;
    #pragma unroll
    for (int jj = 0; jj < 7; ++jj) {
        const float* vrow = QKV + (rbase + (size_t)(start + jj) * 88) * 384 + 256;
        const float pj = s[jj] * inv;
        o0 += pj * vrow[lane];
        o1 += pj * vrow[lane + 64];
    }
    OUT[(size_t)q * 128 + lane] = o0;
    OUT[(size_t)q * 128 + lane + 64] = o1;
}

// ---------------------------------------------------------------------------
// NA1D over p, kernel=87, L=88, heads=1. One block per (b,t) (= 88 rows).
// Window excludes exactly one key: j=87 when i<=43, j=0 when i>=44.
// ---------------------------------------------------------------------------
#define LPAD 133
#define SPAD 89
__launch_bounds__(256)
__global__ void na_f_kernel(const float* __restrict__ QKV,
                            const float* __restrict__ rpb,
                            float* __restrict__ OUT)
{
    __shared__ float Qs[96][LPAD];
    __shared__ float Ks[96][LPAD];   // reused for V in PV phase
    __shared__ float Ss[96][SPAD];
    const int blk = blockIdx.x;                      // b*256 + t
    const int tid = threadIdx.x;
    const size_t base = (size_t)blk * 88 * 384;
    const float scale = 0.08838834764831845f;
    // stage Q (scaled) and K: 88x128 each = 2816 float4 per matrix
    for (int f = tid; f < 2816; f += 256) {
        const int row = f >> 5, c4 = (f & 31) * 4;
        const float4 qv = *(const float4*)(QKV + base + (size_t)row * 384 + c4);
        Qs[row][c4+0] = qv.x * scale; Qs[row][c4+1] = qv.y * scale;
        Qs[row][c4+2] = qv.z * scale; Qs[row][c4+3] = qv.w * scale;
        const float4 kv = *(const float4*)(QKV + base + (size_t)row * 384 + 128 + c4);
        Ks[row][c4+0] = kv.x; Ks[row][c4+1] = kv.y;
        Ks[row][c4+2] = kv.z; Ks[row][c4+3] = kv.w;
    }
    __syncthreads();
    const int tx = tid & 15, ty = tid >> 4;
    { // S = Q K^T
        float acc[6][6] = {};
        for (int kk = 0; kk < 128; ++kk) {
            float a[6], bb[6];
            #pragma unroll
            for (int i = 0; i < 6; ++i) a[i] = Qs[ty*6 + i][kk];
            #pragma unroll
            for (int j = 0; j < 6; ++j) bb[j] = Ks[tx*6 + j][kk];
            #pragma unroll
            for (int i = 0; i < 6; ++i)
                #pragma unroll
                for (int j = 0; j < 6; ++j)
                    acc[i][j] += a[i] * bb[j];
        }
        #pragma unroll
        for (int i = 0; i < 6; ++i) {
            const int qq = ty*6 + i;
            if (qq < 88) {
                #pragma unroll
                for (int j = 0; j < 6; ++j) {
                    const int k = tx*6 + j;
                    if (k < 88) Ss[qq][k] = acc[i][j];
                }
            }
        }
    }
    __syncthreads();
    // stage V into Ks region (K no longer needed)
    for (int f = tid; f < 2816; f += 256) {
        const int row = f >> 5, c4 = (f & 31) * 4;
        const float4 vv = *(const float4*)(QKV + base + (size_t)row * 384 + 256 + c4);
        Ks[row][c4+0] = vv.x; Ks[row][c4+1] = vv.y;
        Ks[row][c4+2] = vv.z; Ks[row][c4+3] = vv.w;
    }
    // softmax per query row (bias + single-key exclusion)
    if (tid < 88) {
        const int i = tid;
        const int jex = (i <= 43) ? 87 : 0;
        float m = -1e30f;
        for (int k = 0; k < 88; ++k) {
            if (k == jex) continue;
            int rel = k - i + 86; if (rel < 0) rel = 0; if (rel > 172) rel = 172;
            const float v = Ss[i][k] + rpb[rel];
            Ss[i][k] = v;
            m = fmaxf(m, v);
        }
        float sum = 0.0f;
        for (int k = 0; k < 88; ++k) {
            if (k == jex) continue;
            const float e = __expf(Ss[i][k] - m);
            Ss[i][k] = e;
            sum += e;
        }
        const float inv = 1.0f / sum;
        for (int k = 0; k < 88; ++k) Ss[i][k] = (k == jex) ? 0.0f : Ss[i][k] * inv;
    }
    __syncthreads();
    { // O = P V ; out[q][d], d = tx + 16*j
        float o[6][8] = {};
        for (int k = 0; k < 88; ++k) {
            float pv[6], vv[8];
            #pragma unroll
            for (int i = 0; i < 6; ++i) pv[i] = Ss[ty*6 + i][k];
            #pragma unroll
            for (int j = 0; j < 8; ++j) vv[j] = Ks[k][tx + 16*j];
            #pragma unroll
            for (int i = 0; i < 6; ++i)
                #pragma unroll
                for (int j = 0; j < 8; ++j)
                    o[i][j] += pv[i] * vv[j];
        }
        #pragma unroll
        for (int i = 0; i < 6; ++i) {
            const int qq = ty*6 + i;
            if (qq < 88) {
                float* dst = OUT + ((size_t)blk * 88 + qq) * 128;
                #pragma unroll
                for (int j = 0; j < 8; ++j) dst[tx + 16*j] = o[i][j];
            }
        }
    }
}

// ---------------------------------------------------------------------------
extern "C" void kernel_launch(void* const* d_in, const int* in_sizes, int n_in,
                              void* d_out, int out_size, void* d_ws, size_t ws_size,
                              hipStream_t stream)
{
    const float* x         = (const float*)d_in[0];
    const float* w_ih_l0   = (const float*)d_in[1];
    const float* w_hh_l0   = (const float*)d_in[2];
    const float* b_ih_l0   = (const float*)d_in[3];
    const float* b_hh_l0   = (const float*)d_in[4];
    const float* w_ih_l0r  = (const float*)d_in[5];
    const float* w_hh_l0r  = (const float*)d_in[6];
    const float* b_ih_l0r  = (const float*)d_in[7];
    const float* b_hh_l0r  = (const float*)d_in[8];
    const float* w_ih_l1   = (const float*)d_in[9];
    const float* w_hh_l1   = (const float*)d_in[10];
    const float* b_ih_l1   = (const float*)d_in[11];
    const float* b_hh_l1   = (const float*)d_in[12];
    const float* w_ih_l1r  = (const float*)d_in[13];
    const float* w_hh_l1r  = (const float*)d_in[14];
    const float* b_ih_l1r  = (const float*)d_in[15];
    const float* b_hh_l1r  = (const float*)d_in[16];
    const float* qkv_w_t   = (const float*)d_in[17];
    const float* qkv_b_t   = (const float*)d_in[18];
    const float* rpb_t     = (const float*)d_in[19];
    const float* proj_w_t  = (const float*)d_in[20];
    const float* proj_b_t  = (const float*)d_in[21];
    const float* qkv_w_f   = (const float*)d_in[22];
    const float* qkv_b_f   = (const float*)d_in[23];
    const float* rpb_f     = (const float*)d_in[24];
    const float* proj_w_f  = (const float*)d_in[25];
    const float* proj_b_f  = (const float*)d_in[26];

    // Workspace layout (276.8 MB total):
    //   XI  region: 90112*512 floats. QKV (90112*384) lives at its base;
    //               ATT (90112*128) lives in the tail -> no aliasing within
    //               any producer/consumer pair.
    //   H0: 90112*128 (reused as G after layer-1 projection consumes it)
    //   H1: 90112*128
    float* ws  = (float*)d_ws;
    float* XI  = ws;                       // 46,137,344 floats
    float* H0  = ws + 46137344;            // 11,534,336 floats
    float* H1  = ws + 57671680;            // 11,534,336 floats
    float* QKV = XI;
    float* ATT = XI + (size_t)MROWS * 384; // tail of XI region
    float* G   = H0;                       // reuse after H0 is dead

    const int BIG = 1 << 30;
    const dim3 blk(256);

    // 1) layer-0 input projection (both directions), A = x view
    gemm_k<1><<<dim3(8, 1408), blk, 0, stream>>>(x, 0, w_ih_l0, w_ih_l0r,
        b_ih_l0, b_hh_l0, b_ih_l0r, b_hh_l0r, XI, 512, 256, 256);
    // 2) layer-0 recurrence
    lstm_kernel<<<dim3(704), blk, 0, stream>>>(XI, w_hh_l0, w_hh_l0r, H0);
    // 3) layer-1 input projection
    gemm_k<0><<<dim3(8, 1408), blk, 0, stream>>>(H0, 128, w_ih_l1, w_ih_l1r,
        b_ih_l1, b_hh_l1, b_ih_l1r, b_hh_l1r, XI, 512, 128, 256);
    // 4) layer-1 recurrence
    lstm_kernel<<<dim3(704), blk, 0, stream>>>(XI, w_hh_l1, w_hh_l1r, H1);
    // 5) QKV for NA over t
    gemm_k<0><<<dim3(6, 1408), blk, 0, stream>>>(H1, 128, qkv_w_t, qkv_w_t,
        qkv_b_t, nullptr, qkv_b_t, nullptr, QKV, 384, 128, BIG);
    // 6) NA over t (kernel=7)
    na_t_kernel<<<dim3(22528), blk, 0, stream>>>(QKV, rpb_t, ATT);
    // 7) proj_t -> G (same (b,t,p) layout; no transpose needed)
    gemm_k<0><<<dim3(2, 1408), blk, 0, stream>>>(ATT, 128, proj_w_t, proj_w_t,
        proj_b_t, nullptr, proj_b_t, nullptr, G, 128, 128, BIG);
    // 8) QKV for NA over p
    gemm_k<0><<<dim3(6, 1408), blk, 0, stream>>>(G, 128, qkv_w_f, qkv_w_f,
        qkv_b_f, nullptr, qkv_b_f, nullptr, QKV, 384, 128, BIG);
    // 9) NA over p (kernel=87, L=88)
    na_f_kernel<<<dim3(1024), blk, 0, stream>>>(QKV, rpb_f, ATT);
    // 10) proj_f -> final output
    gemm_k<0><<<dim3(2, 1408), blk, 0, stream>>>(ATT, 128, proj_w_f, proj_w_f,
        proj_b_f, nullptr, proj_b_f, nullptr, (float*)d_out, 128, 128, BIG);
}

// Round 3
// 1316.789 us; speedup vs baseline: 1.2265x; 1.2265x over previous
//
#include <hip/hip_runtime.h>
#include <cstdint>

#define TP 22528            // 256*88  (t,p) plane size
#define MROWS 90112         // 4*256*88

typedef __bf16 bf16x8 __attribute__((ext_vector_type(8)));
typedef float  f32x4  __attribute__((ext_vector_type(4)));
typedef unsigned short us4v __attribute__((ext_vector_type(4)));

__device__ __forceinline__ unsigned short f2bf(float x) {
    unsigned u = __builtin_bit_cast(unsigned, x);
    return (unsigned short)((u + 0x7fffu + ((u >> 16) & 1u)) >> 16);
}
__device__ __forceinline__ float bf2f(unsigned short h) {
    return __builtin_bit_cast(float, (unsigned)h << 16);
}
// split f32 -> (hi, lo) bf16 pair; hi + lo reproduces x to ~2^-17 relative
__device__ __forceinline__ void cvt4(float a, float b, float c, float d,
                                     us4v& hi, us4v& lo) {
    unsigned short h0 = f2bf(a), h1 = f2bf(b), h2 = f2bf(c), h3 = f2bf(d);
    hi[0] = h0; hi[1] = h1; hi[2] = h2; hi[3] = h3;
    lo[0] = f2bf(a - bf2f(h0)); lo[1] = f2bf(b - bf2f(h1));
    lo[2] = f2bf(c - bf2f(h2)); lo[3] = f2bf(d - bf2f(h3));
}
// swizzled LDS index (ushort units): 64-ushort rows (128 B), XOR 16B-slot
// bits with row&7 -> frag ds_read_b128 lands uniformly on all banks
__device__ __forceinline__ int swz(int r, int c) {
    return r * 64 + (c ^ ((r & 7) << 3));
}

// ---------------------------------------------------------------------------
// MFMA split-bf16 GEMM: C[m, n0+n] = bias[n] + sum_k A[m,k] * W[n,k]
// Tile 128x128, 4 waves in 2x2, each wave 64x64 (4x4 frags of 16x16x32 bf16,
// 3 mfma per frag-pair for the hi/lo split). BK=64 staged in LDS.
// XVIEW: A = x tensor (4,256,256,88); A[m,k] = x[(b*256+k)*TP + (m%TP)].
// Blocks with n0>=splitN use W1/b1a/b1b. NB = N/128. XCD-chunked swizzle so
// the n-blocks sharing an A-panel run on one XCD (L2 reuse).
// ---------------------------------------------------------------------------
template<int XVIEW>
__launch_bounds__(256, 2)
__global__ void gemm_mfma(const float* __restrict__ A, int lda,
                          const float* __restrict__ W0, const float* __restrict__ W1,
                          const float* __restrict__ b0a, const float* __restrict__ b0b,
                          const float* __restrict__ b1a, const float* __restrict__ b1b,
                          float* __restrict__ C, int ldc, int K, int splitN, int NB)
{
    __shared__ unsigned short lds[32768];       // 64 KB: AH|AL|BH|BL tiles
    const int AH = 0, AL = 8192, BH = 16384, BL = 24576;
    const int tid  = threadIdx.x;
    const int bid  = blockIdx.x;
    const int q8   = (int)gridDim.x >> 3;       // bijective XCD-chunk swizzle
    const int w    = (bid & 7) * q8 + (bid >> 3);
    const int nb   = w % NB;
    const int mb   = w / NB;
    const int n0   = nb * 128;
    const int m0   = mb * 128;
    const float* W; const float* ba; const float* bb; int nr0;
    if (n0 < splitN) { W = W0; ba = b0a; bb = b0b; nr0 = n0; }
    else             { W = W1; ba = b1a; bb = b1b; nr0 = n0 - splitN; }
    const int lane = tid & 63;
    const int wave = tid >> 6;
    const int wm   = wave >> 1, wn = wave & 1;
    const int lr   = lane & 15, lg = lane >> 4;
    const int bq   = m0 / TP;               // XVIEW: batch of this m-block
    const int rt0  = m0 - bq * TP;          // (t,p) offset inside the plane

    f32x4 acc[4][4] = {};
    for (int ks = 0; ks < K; ks += 64) {
        // ---- stage A (hi/lo bf16) ----
        if (XVIEW) {
            #pragma unroll
            for (int rep = 0; rep < 8; ++rep) {
                const int u = rep * 256 + tid;
                const int m = u & 127, kq = u >> 7;   // kq in [0,16)
                const float* src = A + (size_t)(bq * 256 + ks + kq * 4) * TP + rt0 + m;
                us4v hi, lo;
                cvt4(src[0], src[TP], src[2 * TP], src[3 * TP], hi, lo);
                *(us4v*)&lds[AH + swz(m, kq * 4)] = hi;
                *(us4v*)&lds[AL + swz(m, kq * 4)] = lo;
            }
        } else {
            #pragma unroll
            for (int rep = 0; rep < 8; ++rep) {
                const int u = rep * 256 + tid;
                const int m = u >> 4, kc = (u & 15) * 4;
                const float4 av = *(const float4*)(A + (size_t)(m0 + m) * lda + ks + kc);
                us4v hi, lo;
                cvt4(av.x, av.y, av.z, av.w, hi, lo);
                *(us4v*)&lds[AH + swz(m, kc)] = hi;
                *(us4v*)&lds[AL + swz(m, kc)] = lo;
            }
        }
        // ---- stage B (weights, hi/lo bf16) ----
        #pragma unroll
        for (int rep = 0; rep < 8; ++rep) {
            const int u = rep * 256 + tid;
            const int n = u >> 4, kc = (u & 15) * 4;
            const float4 wv = *(const float4*)(W + (size_t)(nr0 + n) * K + ks + kc);
            us4v hi, lo;
            cvt4(wv.x, wv.y, wv.z, wv.w, hi, lo);
            *(us4v*)&lds[BH + swz(n, kc)] = hi;
            *(us4v*)&lds[BL + swz(n, kc)] = lo;
        }
        __syncthreads();
        // ---- compute: 2 k-steps of 32 ----
        #pragma unroll
        for (int kk = 0; kk < 64; kk += 32) {
            bf16x8 ah[4], al[4], bh[4], bl[4];
            const int c8 = kk + lg * 8;
            #pragma unroll
            for (int mf = 0; mf < 4; ++mf) {
                const int r = wm * 64 + mf * 16 + lr;
                ah[mf] = *(const bf16x8*)&lds[AH + swz(r, c8)];
                al[mf] = *(const bf16x8*)&lds[AL + swz(r, c8)];
            }
            #pragma unroll
            for (int nf = 0; nf < 4; ++nf) {
                const int r = wn * 64 + nf * 16 + lr;
                bh[nf] = *(const bf16x8*)&lds[BH + swz(r, c8)];
                bl[nf] = *(const bf16x8*)&lds[BL + swz(r, c8)];
            }
            #pragma unroll
            for (int mf = 0; mf < 4; ++mf)
                #pragma unroll
                for (int nf = 0; nf < 4; ++nf) {
                    acc[mf][nf] = __builtin_amdgcn_mfma_f32_16x16x32_bf16(ah[mf], bh[nf], acc[mf][nf], 0, 0, 0);
                    acc[mf][nf] = __builtin_amdgcn_mfma_f32_16x16x32_bf16(ah[mf], bl[nf], acc[mf][nf], 0, 0, 0);
                    acc[mf][nf] = __builtin_amdgcn_mfma_f32_16x16x32_bf16(al[mf], bh[nf], acc[mf][nf], 0, 0, 0);
                }
        }
        __syncthreads();
    }
    // ---- epilogue: D frag col=lane&15, row=(lane>>4)*4+reg [m89] ----
    #pragma unroll
    for (int nf = 0; nf < 4; ++nf) {
        const int ncol = wn * 64 + nf * 16 + lr;
        const float bias = ba[nr0 + ncol] + (bb ? bb[nr0 + ncol] : 0.0f);
        #pragma unroll
        for (int mf = 0; mf < 4; ++mf) {
            const int row = m0 + wm * 64 + mf * 16 + lg * 4;
            #pragma unroll
            for (int i = 0; i < 4; ++i)
                C[(size_t)(row + i) * ldc + n0 + ncol] = acc[mf][nf][i] + bias;
        }
    }
}

// ---------------------------------------------------------------------------
// LSTM recurrence. One block per (sequence row n, direction).
// XI: [MROWS][512] precomputed x@W_ih^T + b_ih + b_hh; fwd gates cols 0..255,
// bwd gates cols 256..511. H out: [MROWS][128], fwd cols 0..63, bwd 64..127.
// thread j in [0,256) owns gate j; threads 0..63 also own (c,h) of unit j.
// Gate order (jnp.split): i | f | g | o.
// ---------------------------------------------------------------------------
__launch_bounds__(256)
__global__ void lstm_kernel(const float* __restrict__ XI,
                            const float* __restrict__ whh_f,
                            const float* __restrict__ whh_b,
                            float* __restrict__ H)
{
    const int bid = blockIdx.x;      // 0..703
    const int dir = bid & 1;
    const int n   = bid >> 1;        // 0..351
    const int b   = n / 88, p = n - 88 * (n / 88);
    const int j   = threadIdx.x;
    const float* whh = dir ? whh_b : whh_f;
    const int j0 = dir ? 256 : 0;
    const int ho = dir ? 64 : 0;
    float w[64];
    #pragma unroll
    for (int k = 0; k < 64; k += 4) {
        const float4 wv = *(const float4*)(whh + (size_t)j * 64 + k);
        w[k] = wv.x; w[k+1] = wv.y; w[k+2] = wv.z; w[k+3] = wv.w;
    }
    __shared__ float h_sh[64];
    __shared__ float acts[256];
    if (j < 64) h_sh[j] = 0.0f;
    float c = 0.0f;
    __syncthreads();
    const size_t rowbase = (size_t)(b * 256) * 88 + p;
    for (int step = 0; step < 256; ++step) {
        const int t = dir ? (255 - step) : step;
        const size_t r = rowbase + (size_t)t * 88;
        float g = XI[r * 512 + j0 + j];
        #pragma unroll
        for (int k = 0; k < 64; k += 4) {
            const float4 h4 = *(const float4*)&h_sh[k];
            g += h4.x * w[k] + h4.y * w[k+1] + h4.z * w[k+2] + h4.w * w[k+3];
        }
        float a;
        if (j >= 128 && j < 192) {            // g-gate: tanh (wave-uniform branch)
            float e = __expf(2.0f * g);
            a = 1.0f - 2.0f / (e + 1.0f);
        } else {                              // i,f,o: sigmoid
            a = 1.0f / (1.0f + __expf(-g));
        }
        acts[j] = a;
        __syncthreads();
        if (j < 64) {
            float ai = acts[j], af = acts[64 + j], ag = acts[128 + j], ao = acts[192 + j];
            c = af * c + ai * ag;
            float e = __expf(2.0f * c);
            float th = 1.0f - 2.0f / (e + 1.0f);
            float h = ao * th;
            h_sh[j] = h;
            H[r * 128 + ho + j] = h;
        }
        __syncthreads();
    }
}

// ---------------------------------------------------------------------------
// NA1D over t, kernel=7, heads=1. One wave per query row.
// QKV: [MROWS][384] (q|k|v), rows in (b,t,p) order. OUT: [MROWS][128].
// ---------------------------------------------------------------------------
__launch_bounds__(256)
__global__ void na_t_kernel(const float* __restrict__ QKV,
                            const float* __restrict__ rpb,
                            float* __restrict__ OUT)
{
    const int wave = threadIdx.x >> 6;
    const int lane = threadIdx.x & 63;
    const int q = blockIdx.x * 4 + wave;          // row index r = (b*256+i)*88+p
    const int b = q / TP; int rem = q - b * TP;
    const int i = rem / 88; const int p = rem - 88 * (rem / 88);
    int start = i - 3; if (start < 0) start = 0; if (start > 249) start = 249;
    const float scale = 0.08838834764831845f;     // 128^-0.5
    const float* qrow = QKV + (size_t)q * 384;
    const float q0 = qrow[lane] * scale;
    const float q1 = qrow[lane + 64] * scale;
    const size_t rbase = (size_t)(b * 256) * 88 + p;
    float s[7];
    #pragma unroll
    for (int jj = 0; jj < 7; ++jj) {
        const int t = start + jj;
        const float* krow = QKV + (rbase + (size_t)t * 88) * 384 + 128;
        float part = q0 * krow[lane] + q1 * krow[lane + 64];
        part += __shfl_xor(part, 1);
        part += __shfl_xor(part, 2);
        part += __shfl_xor(part, 4);
        part += __shfl_xor(part, 8);
        part += __shfl_xor(part, 16);
        part += __shfl_xor(part, 32);
        int rel = t - i + 6; if (rel < 0) rel = 0; if (rel > 12) rel = 12;
        s[jj] = part + rpb[rel];
    }
    float m = s[0];
    #pragma unroll
    for (int jj = 1; jj < 7; ++jj) m = fmaxf(m, s[jj]);
    float sum = 0.0f;
    #pragma unroll
    for (int jj = 0; jj < 7; ++jj) { s[jj] = __expf(s[jj] - m); sum += s[jj]; }
    const float inv = 1.0f / sum;
    float o0 = 0.0f, o1 = 0.0f;
    #pragma unroll
    for (int jj = 0; jj < 7; ++jj) {
        const float* vrow = QKV + (rbase + (size_t)(start + jj) * 88) * 384 + 256;
        const float pj = s[jj] * inv;
        o0 += pj * vrow[lane];
        o1 += pj * vrow[lane + 64];
    }
    OUT[(size_t)q * 128 + lane] = o0;
    OUT[(size_t)q * 128 + lane + 64] = o1;
}

// ---------------------------------------------------------------------------
// NA1D over p, kernel=87, L=88, heads=1. One block per (b,t) (= 88 rows).
// Window excludes exactly one key: j=87 when i<=43, j=0 when i>=44.
// ---------------------------------------------------------------------------
#define LPAD 133
#define SPAD 89
__launch_bounds__(256)
__global__ void na_f_kernel(const float* __restrict__ QKV,
                            const float* __restrict__ rpb,
                            float* __restrict__ OUT)
{
    __shared__ float Qs[96][LPAD];
    __shared__ float Ks[96][LPAD];   // reused for V in PV phase
    __shared__ float Ss[96][SPAD];
    const int blk = blockIdx.x;                      // b*256 + t
    const int tid = threadIdx.x;
    const size_t base = (size_t)blk * 88 * 384;
    const float scale = 0.08838834764831845f;
    // stage Q (scaled) and K: 88x128 each = 2816 float4 per matrix
    for (int f = tid; f < 2816; f += 256) {
        const int row = f >> 5, c4 = (f & 31) * 4;
        const float4 qv = *(const float4*)(QKV + base + (size_t)row * 384 + c4);
        Qs[row][c4+0] = qv.x * scale; Qs[row][c4+1] = qv.y * scale;
        Qs[row][c4+2] = qv.z * scale; Qs[row][c4+3] = qv.w * scale;
        const float4 kv = *(const float4*)(QKV + base + (size_t)row * 384 + 128 + c4);
        Ks[row][c4+0] = kv.x; Ks[row][c4+1] = kv.y;
        Ks[row][c4+2] = kv.z; Ks[row][c4+3] = kv.w;
    }
    __syncthreads();
    const int tx = tid & 15, ty = tid >> 4;
    { // S = Q K^T
        float acc[6][6] = {};
        for (int kk = 0; kk < 128; ++kk) {
            float a[6], bb[6];
            #pragma unroll
            for (int i = 0; i < 6; ++i) a[i] = Qs[ty*6 + i][kk];
            #pragma unroll
            for (int j = 0; j < 6; ++j) bb[j] = Ks[tx*6 + j][kk];
            #pragma unroll
            for (int i = 0; i < 6; ++i)
                #pragma unroll
                for (int j = 0; j < 6; ++j)
                    acc[i][j] += a[i] * bb[j];
        }
        #pragma unroll
        for (int i = 0; i < 6; ++i) {
            const int qq = ty*6 + i;
            if (qq < 88) {
                #pragma unroll
                for (int j = 0; j < 6; ++j) {
                    const int k = tx*6 + j;
                    if (k < 88) Ss[qq][k] = acc[i][j];
                }
            }
        }
    }
    __syncthreads();
    // stage V into Ks region (K no longer needed)
    for (int f = tid; f < 2816; f += 256) {
        const int row = f >> 5, c4 = (f & 31) * 4;
        const float4 vv = *(const float4*)(QKV + base + (size_t)row * 384 + 256 + c4);
        Ks[row][c4+0] = vv.x; Ks[row][c4+1] = vv.y;
        Ks[row][c4+2] = vv.z; Ks[row][c4+3] = vv.w;
    }
    // softmax per query row (bias + single-key exclusion)
    if (tid < 88) {
        const int i = tid;
        const int jex = (i <= 43) ? 87 : 0;
        float m = -1e30f;
        for (int k = 0; k < 88; ++k) {
            if (k == jex) continue;
            int rel = k - i + 86; if (rel < 0) rel = 0; if (rel > 172) rel = 172;
            const float v = Ss[i][k] + rpb[rel];
            Ss[i][k] = v;
            m = fmaxf(m, v);
        }
        float sum = 0.0f;
        for (int k = 0; k < 88; ++k) {
            if (k == jex) continue;
            const float e = __expf(Ss[i][k] - m);
            Ss[i][k] = e;
            sum += e;
        }
        const float inv = 1.0f / sum;
        for (int k = 0; k < 88; ++k) Ss[i][k] = (k == jex) ? 0.0f : Ss[i][k] * inv;
    }
    __syncthreads();
    { // O = P V ; out[q][d], d = tx + 16*j
        float o[6][8] = {};
        for (int k = 0; k < 88; ++k) {
            float pv[6], vv[8];
            #pragma unroll
            for (int i = 0; i < 6; ++i) pv[i] = Ss[ty*6 + i][k];
            #pragma unroll
            for (int j = 0; j < 8; ++j) vv[j] = Ks[k][tx + 16*j];
            #pragma unroll
            for (int i = 0; i < 6; ++i)
                #pragma unroll
                for (int j = 0; j < 8; ++j)
                    o[i][j] += pv[i] * vv[j];
        }
        #pragma unroll
        for (int i = 0; i < 6; ++i) {
            const int qq = ty*6 + i;
            if (qq < 88) {
                float* dst = OUT + ((size_t)blk * 88 + qq) * 128;
                #pragma unroll
                for (int j = 0; j < 8; ++j) dst[tx + 16*j] = o[i][j];
            }
        }
    }
}

// ---------------------------------------------------------------------------
extern "C" void kernel_launch(void* const* d_in, const int* in_sizes, int n_in,
                              void* d_out, int out_size, void* d_ws, size_t ws_size,
                              hipStream_t stream)
{
    const float* x         = (const float*)d_in[0];
    const float* w_ih_l0   = (const float*)d_in[1];
    const float* w_hh_l0   = (const float*)d_in[2];
    const float* b_ih_l0   = (const float*)d_in[3];
    const float* b_hh_l0   = (const float*)d_in[4];
    const float* w_ih_l0r  = (const float*)d_in[5];
    const float* w_hh_l0r  = (const float*)d_in[6];
    const float* b_ih_l0r  = (const float*)d_in[7];
    const float* b_hh_l0r  = (const float*)d_in[8];
    const float* w_ih_l1   = (const float*)d_in[9];
    const float* w_hh_l1   = (const float*)d_in[10];
    const float* b_ih_l1   = (const float*)d_in[11];
    const float* b_hh_l1   = (const float*)d_in[12];
    const float* w_ih_l1r  = (const float*)d_in[13];
    const float* w_hh_l1r  = (const float*)d_in[14];
    const float* b_ih_l1r  = (const float*)d_in[15];
    const float* b_hh_l1r  = (const float*)d_in[16];
    const float* qkv_w_t   = (const float*)d_in[17];
    const float* qkv_b_t   = (const float*)d_in[18];
    const float* rpb_t     = (const float*)d_in[19];
    const float* proj_w_t  = (const float*)d_in[20];
    const float* proj_b_t  = (const float*)d_in[21];
    const float* qkv_w_f   = (const float*)d_in[22];
    const float* qkv_b_f   = (const float*)d_in[23];
    const float* rpb_f     = (const float*)d_in[24];
    const float* proj_w_f  = (const float*)d_in[25];
    const float* proj_b_f  = (const float*)d_in[26];

    // Workspace layout (276.8 MB total):
    //   XI  region: 90112*512 floats. QKV (90112*384) lives at its base;
    //               ATT (90112*128) lives in the tail -> no aliasing within
    //               any producer/consumer pair.
    //   H0: 90112*128 (reused as G after layer-1 projection consumes it)
    //   H1: 90112*128
    float* ws  = (float*)d_ws;
    float* XI  = ws;                       // 46,137,344 floats
    float* H0  = ws + 46137344;            // 11,534,336 floats
    float* H1  = ws + 57671680;            // 11,534,336 floats
    float* QKV = XI;
    float* ATT = XI + (size_t)MROWS * 384; // tail of XI region
    float* G   = H0;                       // reuse after H0 is dead

    const int BIG = 1 << 30;
    const dim3 blk(256);

    // 1) layer-0 input projection (both directions), A = x view
    gemm_mfma<1><<<dim3(2816), blk, 0, stream>>>(x, 0, w_ih_l0, w_ih_l0r,
        b_ih_l0, b_hh_l0, b_ih_l0r, b_hh_l0r, XI, 512, 256, 256, 4);
    // 2) layer-0 recurrence
    lstm_kernel<<<dim3(704), blk, 0, stream>>>(XI, w_hh_l0, w_hh_l0r, H0);
    // 3) layer-1 input projection
    gemm_mfma<0><<<dim3(2816), blk, 0, stream>>>(H0, 128, w_ih_l1, w_ih_l1r,
        b_ih_l1, b_hh_l1, b_ih_l1r, b_hh_l1r, XI, 512, 128, 256, 4);
    // 4) layer-1 recurrence
    lstm_kernel<<<dim3(704), blk, 0, stream>>>(XI, w_hh_l1, w_hh_l1r, H1);
    // 5) QKV for NA over t
    gemm_mfma<0><<<dim3(2112), blk, 0, stream>>>(H1, 128, qkv_w_t, qkv_w_t,
        qkv_b_t, nullptr, qkv_b_t, nullptr, QKV, 384, 128, BIG, 3);
    // 6) NA over t (kernel=7)
    na_t_kernel<<<dim3(22528), blk, 0, stream>>>(QKV, rpb_t, ATT);
    // 7) proj_t -> G (same (b,t,p) layout; no transpose needed)
    gemm_mfma<0><<<dim3(704), blk, 0, stream>>>(ATT, 128, proj_w_t, proj_w_t,
        proj_b_t, nullptr, proj_b_t, nullptr, G, 128, 128, BIG, 1);
    // 8) QKV for NA over p
    gemm_mfma<0><<<dim3(2112), blk, 0, stream>>>(G, 128, qkv_w_f, qkv_w_f,
        qkv_b_f, nullptr, qkv_b_f, nullptr, QKV, 384, 128, BIG, 3);
    // 9) NA over p (kernel=87, L=88)
    na_f_kernel<<<dim3(1024), blk, 0, stream>>>(QKV, rpb_f, ATT);
    // 10) proj_f -> final output
    gemm_mfma<0><<<dim3(704), blk, 0, stream>>>(ATT, 128, proj_w_f, proj_w_f,
        proj_b_f, nullptr, proj_b_f, nullptr, (float*)d_out, 128, 128, BIG, 1);
}

// Round 4
// 1103.656 us; speedup vs baseline: 1.4634x; 1.1931x over previous
//
#include <hip/hip_runtime.h>
#include <cstdint>

#define TP 22528            // 256*88  (t,p) plane size
#define MROWS 90112         // 4*256*88

typedef __bf16 bf16x8 __attribute__((ext_vector_type(8)));
typedef float  f32x4  __attribute__((ext_vector_type(4)));
typedef unsigned short ushort8 __attribute__((ext_vector_type(8)));

__device__ __forceinline__ unsigned short f2bf(float x) {
    unsigned u = __builtin_bit_cast(unsigned, x);
    return (unsigned short)((u + 0x7fffu + ((u >> 16) & 1u)) >> 16);
}
__device__ __forceinline__ float bf2f(unsigned short h) {
    return __builtin_bit_cast(float, (unsigned)h << 16);
}
__device__ __forceinline__ void gl16(const void* g, void* l) {
    __builtin_amdgcn_global_load_lds(
        (const __attribute__((address_space(1))) void*)g,
        (__attribute__((address_space(3))) void*)l, 16, 0, 0);
}

// ---------------------------------------------------------------------------
// convert all 8 weight matrices f32 -> (hi,lo) bf16, concatenated in WH/WL.
// segments: w_ih_l0(65536) w_ih_l0r(65536) w_ih_l1(32768) w_ih_l1r(32768)
//           qkv_w_t(49152) proj_w_t(16384) qkv_w_f(49152) proj_w_f(16384)
// ---------------------------------------------------------------------------
__global__ void convert_w(const float* __restrict__ s0, const float* __restrict__ s1,
                          const float* __restrict__ s2, const float* __restrict__ s3,
                          const float* __restrict__ s4, const float* __restrict__ s5,
                          const float* __restrict__ s6, const float* __restrict__ s7,
                          unsigned short* __restrict__ WH, unsigned short* __restrict__ WL)
{
    const int stride = gridDim.x * blockDim.x;
    for (int i = blockIdx.x * blockDim.x + threadIdx.x; i < 327680; i += stride) {
        const float* s; int base;
        if      (i <  65536) { s = s0; base = 0; }
        else if (i < 131072) { s = s1; base = 65536; }
        else if (i < 163840) { s = s2; base = 131072; }
        else if (i < 196608) { s = s3; base = 163840; }
        else if (i < 245760) { s = s4; base = 196608; }
        else if (i < 262144) { s = s5; base = 245760; }
        else if (i < 311296) { s = s6; base = 262144; }
        else                 { s = s7; base = 311296; }
        const float v = s[i - base];
        const unsigned short h = f2bf(v);
        WH[i] = h; WL[i] = f2bf(v - bf2f(h));
    }
}

// ---------------------------------------------------------------------------
// x (4, 256, 256, 88) f32  ->  Xhi/Xlo [m=(b,t,p)][k=256] bf16 (tiled transpose)
// ---------------------------------------------------------------------------
__launch_bounds__(256)
__global__ void transpose_x(const float* __restrict__ x,
                            unsigned short* __restrict__ Xh,
                            unsigned short* __restrict__ Xl)
{
    __shared__ float tile[64][65];
    const int tid = threadIdx.x;
    const int tp0 = blockIdx.x * 64, k0 = blockIdx.y * 64, b = blockIdx.z;
    #pragma unroll
    for (int i = 0; i < 16; ++i) {
        const int idx = i * 256 + tid;
        const int kl = idx >> 6, tpl = idx & 63;
        tile[kl][tpl] = x[(size_t)(b * 256 + k0 + kl) * TP + tp0 + tpl];
    }
    __syncthreads();
    #pragma unroll
    for (int i = 0; i < 2; ++i) {
        const int u = i * 2048 + tid * 8;
        const int ml = u >> 6, kl0 = u & 63;
        ushort8 hi, lo;
        #pragma unroll
        for (int j = 0; j < 8; ++j) {
            const float v = tile[kl0 + j][ml];
            const unsigned short h = f2bf(v);
            hi[j] = h; lo[j] = f2bf(v - bf2f(h));
        }
        const size_t row = (size_t)b * TP + tp0 + ml;
        *(ushort8*)&Xh[row * 256 + k0 + kl0] = hi;
        *(ushort8*)&Xl[row * 256 + k0 + kl0] = lo;
    }
}

// ---------------------------------------------------------------------------
// MFMA split-bf16 GEMM, pre-converted operands.
// C[m, n0+n] = bias[n] + sum_k A[m,k]*W[n,k],  A=(Ahi+Alo), W=(Whi+Wlo),
// products: hh + hl + lh (3 mfma). Tile 128x128, BK=32, 4 waves 2x2 (64x64
// each). Double-buffered 64 KB LDS staged via global_load_lds (16B), counted
// vmcnt(8), raw s_barrier. Read-side XOR swizzle slot^=(row&3) paired with
// inverse-swizzled global source (both-sides involution).
// Blocks with n0>=splitN use W1 set. NB = N/128; grid = 704*NB (div by 8).
// ---------------------------------------------------------------------------
template<int OUTBF>
__launch_bounds__(256, 2)
__global__ void gemm_bf16(const unsigned short* __restrict__ Ahi,
                          const unsigned short* __restrict__ Alo,
                          const unsigned short* __restrict__ Whi0,
                          const unsigned short* __restrict__ Wlo0,
                          const unsigned short* __restrict__ Whi1,
                          const unsigned short* __restrict__ Wlo1,
                          const float* __restrict__ b0a, const float* __restrict__ b0b,
                          const float* __restrict__ b1a, const float* __restrict__ b1b,
                          float* __restrict__ C,
                          unsigned short* __restrict__ Chi, unsigned short* __restrict__ Clo,
                          int ldc, int K, int splitN, int NB)
{
    __shared__ unsigned short lds[32768];   // 2 bufs x (AH|AL|BH|BL) x 8KB
    const int tid  = threadIdx.x;
    const int bid  = blockIdx.x;
    const int q8   = (int)gridDim.x >> 3;
    const int wq   = (bid & 7) * q8 + (bid >> 3);   // bijective XCD swizzle
    const int nb   = wq % NB;
    const int mb   = wq / NB;
    const int n0   = nb * 128;
    const int m0   = mb * 128;
    const unsigned short* Wh; const unsigned short* Wl;
    const float* ba; const float* bb; int nr0;
    if (n0 < splitN) { Wh = Whi0; Wl = Wlo0; ba = b0a; bb = b0b; nr0 = n0; }
    else             { Wh = Whi1; Wl = Wlo1; ba = b1a; bb = b1b; nr0 = n0 - splitN; }
    const int lane = tid & 63;
    const int wv   = tid >> 6;
    const int wm   = wv >> 1, wn = wv & 1;
    const int lr   = lane & 15, lg = lane >> 4;
    // staging: lane covers row (l>>2) of its 16-row chunk, slot (l&3);
    // source slot pre-swizzled by row&3 (inverse of the read-side XOR).
    const int voff = (lane >> 2) * K + (((lane & 3) ^ ((lane >> 2) & 3)) * 8);
    const int wb   = wv * 1024;                      // wave's LDS row area

    const unsigned short* gAh = Ahi + (size_t)(m0 + wv * 32) * K + voff;
    const unsigned short* gAl = Alo + (size_t)(m0 + wv * 32) * K + voff;
    const unsigned short* gBh = Wh + (size_t)(nr0 + wv * 32) * K + voff;
    const unsigned short* gBl = Wl + (size_t)(nr0 + wv * 32) * K + voff;

    const int NT = K >> 5;
    f32x4 acc[4][4] = {};

    auto stage = [&](int bufi, int ks) {
        unsigned short* base = lds + bufi * 16384;
        gl16(gAh + ks,          base +         wb);
        gl16(gAh + ks + 16 * K, base +         wb + 512);
        gl16(gAl + ks,          base + 4096  + wb);
        gl16(gAl + ks + 16 * K, base + 4096  + wb + 512);
        gl16(gBh + ks,          base + 8192  + wb);
        gl16(gBh + ks + 16 * K, base + 8192  + wb + 512);
        gl16(gBl + ks,          base + 12288 + wb);
        gl16(gBl + ks + 16 * K, base + 12288 + wb + 512);
    };

    stage(0, 0);
    for (int t = 0; t < NT; ++t) {
        const int cur = (t & 1) * 16384;
        if (t + 1 < NT) {
            stage((t & 1) ^ 1, (t + 1) * 32);
            asm volatile("s_waitcnt vmcnt(8)" ::: "memory");
        } else {
            asm volatile("s_waitcnt vmcnt(0)" ::: "memory");
        }
        __builtin_amdgcn_s_barrier();
        __builtin_amdgcn_sched_barrier(0);
        bf16x8 ah[4], al[4], bh[4], bl[4];
        #pragma unroll
        for (int mf = 0; mf < 4; ++mf) {
            const int r = wm * 64 + mf * 16 + lr;
            const int o = r * 32 + ((lg ^ (r & 3)) * 8);
            ah[mf] = *(const bf16x8*)&lds[cur + o];
            al[mf] = *(const bf16x8*)&lds[cur + 4096 + o];
        }
        #pragma unroll
        for (int nf = 0; nf < 4; ++nf) {
            const int r = wn * 64 + nf * 16 + lr;
            const int o = r * 32 + ((lg ^ (r & 3)) * 8);
            bh[nf] = *(const bf16x8*)&lds[cur + 8192 + o];
            bl[nf] = *(const bf16x8*)&lds[cur + 12288 + o];
        }
        #pragma unroll
        for (int mf = 0; mf < 4; ++mf)
            #pragma unroll
            for (int nf = 0; nf < 4; ++nf) {
                acc[mf][nf] = __builtin_amdgcn_mfma_f32_16x16x32_bf16(ah[mf], bh[nf], acc[mf][nf], 0, 0, 0);
                acc[mf][nf] = __builtin_amdgcn_mfma_f32_16x16x32_bf16(ah[mf], bl[nf], acc[mf][nf], 0, 0, 0);
                acc[mf][nf] = __builtin_amdgcn_mfma_f32_16x16x32_bf16(al[mf], bh[nf], acc[mf][nf], 0, 0, 0);
            }
        __builtin_amdgcn_s_barrier();
        __builtin_amdgcn_sched_barrier(0);
    }
    // epilogue: D frag col=lane&15, row=(lane>>4)*4+reg  [m89]
    #pragma unroll
    for (int nf = 0; nf < 4; ++nf) {
        const int ncol = wn * 64 + nf * 16 + lr;
        const float bias = ba[nr0 + ncol] + (bb ? bb[nr0 + ncol] : 0.0f);
        #pragma unroll
        for (int mf = 0; mf < 4; ++mf) {
            const int row = m0 + wm * 64 + mf * 16 + lg * 4;
            #pragma unroll
            for (int i = 0; i < 4; ++i) {
                const float v = acc[mf][nf][i] + bias;
                if (OUTBF) {
                    const size_t o = (size_t)(row + i) * ldc + n0 + ncol;
                    const unsigned short h = f2bf(v);
                    Chi[o] = h; Clo[o] = f2bf(v - bf2f(h));
                } else {
                    C[(size_t)(row + i) * ldc + n0 + ncol] = v;
                }
            }
        }
    }
}

// ---------------------------------------------------------------------------
// LSTM recurrence. One block per (sequence row n, direction).
// XI: [MROWS][512] f32 precomputed x@W_ih^T + b_ih + b_hh. H out: hi/lo bf16
// planes [MROWS][128] (fwd cols 0..63, bwd 64..127). Gate order i|f|g|o.
// ---------------------------------------------------------------------------
__launch_bounds__(256)
__global__ void lstm_kernel(const float* __restrict__ XI,
                            const float* __restrict__ whh_f,
                            const float* __restrict__ whh_b,
                            unsigned short* __restrict__ Hh,
                            unsigned short* __restrict__ Hl)
{
    const int bid = blockIdx.x;      // 0..703
    const int dir = bid & 1;
    const int n   = bid >> 1;        // 0..351
    const int b   = n / 88, p = n - 88 * (n / 88);
    const int j   = threadIdx.x;
    const float* whh = dir ? whh_b : whh_f;
    const int j0 = dir ? 256 : 0;
    const int ho = dir ? 64 : 0;
    float w[64];
    #pragma unroll
    for (int k = 0; k < 64; k += 4) {
        const float4 wv = *(const float4*)(whh + (size_t)j * 64 + k);
        w[k] = wv.x; w[k+1] = wv.y; w[k+2] = wv.z; w[k+3] = wv.w;
    }
    __shared__ float h_sh[64];
    __shared__ float acts[256];
    if (j < 64) h_sh[j] = 0.0f;
    float c = 0.0f;
    __syncthreads();
    const size_t rowbase = (size_t)(b * 256) * 88 + p;
    float pref = XI[(rowbase + (size_t)(dir ? 255 : 0) * 88) * 512 + j0 + j];
    for (int step = 0; step < 256; ++step) {
        const int t = dir ? (255 - step) : step;
        const size_t r = rowbase + (size_t)t * 88;
        float gs0 = pref, gs1 = 0.0f, gs2 = 0.0f, gs3 = 0.0f;
        if (step + 1 < 256) {   // prefetch next step's xi (hides HBM latency)
            const int tn = dir ? (254 - step) : (step + 1);
            pref = XI[(rowbase + (size_t)tn * 88) * 512 + j0 + j];
        }
        #pragma unroll
        for (int k = 0; k < 64; k += 16) {
            const float4 h0 = *(const float4*)&h_sh[k];
            const float4 h1 = *(const float4*)&h_sh[k + 4];
            const float4 h2 = *(const float4*)&h_sh[k + 8];
            const float4 h3 = *(const float4*)&h_sh[k + 12];
            gs0 += h0.x * w[k]    + h0.y * w[k+1]  + h0.z * w[k+2]  + h0.w * w[k+3];
            gs1 += h1.x * w[k+4]  + h1.y * w[k+5]  + h1.z * w[k+6]  + h1.w * w[k+7];
            gs2 += h2.x * w[k+8]  + h2.y * w[k+9]  + h2.z * w[k+10] + h2.w * w[k+11];
            gs3 += h3.x * w[k+12] + h3.y * w[k+13] + h3.z * w[k+14] + h3.w * w[k+15];
        }
        const float g = (gs0 + gs1) + (gs2 + gs3);
        float a;
        if (j >= 128 && j < 192) {            // g-gate: tanh (wave-uniform)
            const float e = __expf(2.0f * g);
            a = 1.0f - 2.0f / (e + 1.0f);
        } else {                              // i,f,o: sigmoid
            a = 1.0f / (1.0f + __expf(-g));
        }
        acts[j] = a;
        __syncthreads();
        if (j < 64) {
            const float ai = acts[j], af = acts[64 + j], ag = acts[128 + j], ao = acts[192 + j];
            c = af * c + ai * ag;
            const float e = __expf(2.0f * c);
            const float th = 1.0f - 2.0f / (e + 1.0f);
            const float h = ao * th;
            h_sh[j] = h;
            const size_t o = r * 128 + ho + j;
            const unsigned short hh = f2bf(h);
            Hh[o] = hh; Hl[o] = f2bf(h - bf2f(hh));
        }
        __syncthreads();
    }
}

// ---------------------------------------------------------------------------
// NA1D over t, kernel=7, heads=1. One wave per query row.
// QKV: [MROWS][384] f32 (q|k|v). OUT: hi/lo bf16 [MROWS][128].
// ---------------------------------------------------------------------------
__launch_bounds__(256)
__global__ void na_t_kernel(const float* __restrict__ QKV,
                            const float* __restrict__ rpb,
                            unsigned short* __restrict__ OUTh,
                            unsigned short* __restrict__ OUTl)
{
    const int wave = threadIdx.x >> 6;
    const int lane = threadIdx.x & 63;
    const int q = blockIdx.x * 4 + wave;          // row r = (b*256+i)*88+p
    const int b = q / TP; int rem = q - b * TP;
    const int i = rem / 88; const int p = rem - 88 * (rem / 88);
    int start = i - 3; if (start < 0) start = 0; if (start > 249) start = 249;
    const float scale = 0.08838834764831845f;     // 128^-0.5
    const float* qrow = QKV + (size_t)q * 384;
    const float q0 = qrow[lane] * scale;
    const float q1 = qrow[lane + 64] * scale;
    const size_t rbase = (size_t)(b * 256) * 88 + p;
    float s[7];
    #pragma unroll
    for (int jj = 0; jj < 7; ++jj) {
        const int t = start + jj;
        const float* krow = QKV + (rbase + (size_t)t * 88) * 384 + 128;
        float part = q0 * krow[lane] + q1 * krow[lane + 64];
        part += __shfl_xor(part, 1);
        part += __shfl_xor(part, 2);
        part += __shfl_xor(part, 4);
        part += __shfl_xor(part, 8);
        part += __shfl_xor(part, 16);
        part += __shfl_xor(part, 32);
        int rel = t - i + 6; if (rel < 0) rel = 0; if (rel > 12) rel = 12;
        s[jj] = part + rpb[rel];
    }
    float m = s[0];
    #pragma unroll
    for (int jj = 1; jj < 7; ++jj) m = fmaxf(m, s[jj]);
    float sum = 0.0f;
    #pragma unroll
    for (int jj = 0; jj < 7; ++jj) { s[jj] = __expf(s[jj] - m); sum += s[jj]; }
    const float inv = 1.0f / sum;
    float o0 = 0.0f, o1 = 0.0f;
    #pragma unroll
    for (int jj = 0; jj < 7; ++jj) {
        const float* vrow = QKV + (rbase + (size_t)(start + jj) * 88) * 384 + 256;
        const float pj = s[jj] * inv;
        o0 += pj * vrow[lane];
        o1 += pj * vrow[lane + 64];
    }
    const size_t oi = (size_t)q * 128 + lane;
    const unsigned short h0 = f2bf(o0);
    OUTh[oi] = h0; OUTl[oi] = f2bf(o0 - bf2f(h0));
    const unsigned short h1 = f2bf(o1);
    OUTh[oi + 64] = h1; OUTl[oi + 64] = f2bf(o1 - bf2f(h1));
}

// ---------------------------------------------------------------------------
// NA1D over p, kernel=87, L=88, heads=1. One block per (b,t).
// Excluded key: j=87 when i<=43, j=0 when i>=44. OUT: hi/lo bf16.
// ---------------------------------------------------------------------------
#define LPAD 133
#define SPAD 89
__launch_bounds__(256)
__global__ void na_f_kernel(const float* __restrict__ QKV,
                            const float* __restrict__ rpb,
                            unsigned short* __restrict__ OUTh,
                            unsigned short* __restrict__ OUTl)
{
    __shared__ float Qs[96][LPAD];
    __shared__ float Ks[96][LPAD];   // reused for V in PV phase
    __shared__ float Ss[96][SPAD];
    const int blk = blockIdx.x;                      // b*256 + t
    const int tid = threadIdx.x;
    const size_t base = (size_t)blk * 88 * 384;
    const float scale = 0.08838834764831845f;
    for (int f = tid; f < 2816; f += 256) {
        const int row = f >> 5, c4 = (f & 31) * 4;
        const float4 qv = *(const float4*)(QKV + base + (size_t)row * 384 + c4);
        Qs[row][c4+0] = qv.x * scale; Qs[row][c4+1] = qv.y * scale;
        Qs[row][c4+2] = qv.z * scale; Qs[row][c4+3] = qv.w * scale;
        const float4 kv = *(const float4*)(QKV + base + (size_t)row * 384 + 128 + c4);
        Ks[row][c4+0] = kv.x; Ks[row][c4+1] = kv.y;
        Ks[row][c4+2] = kv.z; Ks[row][c4+3] = kv.w;
    }
    __syncthreads();
    const int tx = tid & 15, ty = tid >> 4;
    { // S = Q K^T
        float acc[6][6] = {};
        for (int kk = 0; kk < 128; ++kk) {
            float a[6], bb[6];
            #pragma unroll
            for (int i = 0; i < 6; ++i) a[i] = Qs[ty*6 + i][kk];
            #pragma unroll
            for (int j = 0; j < 6; ++j) bb[j] = Ks[tx*6 + j][kk];
            #pragma unroll
            for (int i = 0; i < 6; ++i)
                #pragma unroll
                for (int j = 0; j < 6; ++j)
                    acc[i][j] += a[i] * bb[j];
        }
        #pragma unroll
        for (int i = 0; i < 6; ++i) {
            const int qq = ty*6 + i;
            if (qq < 88) {
                #pragma unroll
                for (int j = 0; j < 6; ++j) {
                    const int k = tx*6 + j;
                    if (k < 88) Ss[qq][k] = acc[i][j];
                }
            }
        }
    }
    __syncthreads();
    // stage V into Ks region (K no longer needed)
    for (int f = tid; f < 2816; f += 256) {
        const int row = f >> 5, c4 = (f & 31) * 4;
        const float4 vv = *(const float4*)(QKV + base + (size_t)row * 384 + 256 + c4);
        Ks[row][c4+0] = vv.x; Ks[row][c4+1] = vv.y;
        Ks[row][c4+2] = vv.z; Ks[row][c4+3] = vv.w;
    }
    if (tid < 88) {
        const int i = tid;
        const int jex = (i <= 43) ? 87 : 0;
        float m = -1e30f;
        for (int k = 0; k < 88; ++k) {
            if (k == jex) continue;
            int rel = k - i + 86; if (rel < 0) rel = 0; if (rel > 172) rel = 172;
            const float v = Ss[i][k] + rpb[rel];
            Ss[i][k] = v;
            m = fmaxf(m, v);
        }
        float sum = 0.0f;
        for (int k = 0; k < 88; ++k) {
            if (k == jex) continue;
            const float e = __expf(Ss[i][k] - m);
            Ss[i][k] = e;
            sum += e;
        }
        const float inv = 1.0f / sum;
        for (int k = 0; k < 88; ++k) Ss[i][k] = (k == jex) ? 0.0f : Ss[i][k] * inv;
    }
    __syncthreads();
    { // O = P V
        float o[6][8] = {};
        for (int k = 0; k < 88; ++k) {
            float pv[6], vv[8];
            #pragma unroll
            for (int i = 0; i < 6; ++i) pv[i] = Ss[ty*6 + i][k];
            #pragma unroll
            for (int j = 0; j < 8; ++j) vv[j] = Ks[k][tx + 16*j];
            #pragma unroll
            for (int i = 0; i < 6; ++i)
                #pragma unroll
                for (int j = 0; j < 8; ++j)
                    o[i][j] += pv[i] * vv[j];
        }
        #pragma unroll
        for (int i = 0; i < 6; ++i) {
            const int qq = ty*6 + i;
            if (qq < 88) {
                const size_t ro = ((size_t)blk * 88 + qq) * 128;
                #pragma unroll
                for (int j = 0; j < 8; ++j) {
                    const float v = o[i][j];
                    const unsigned short hh = f2bf(v);
                    OUTh[ro + tx + 16*j] = hh;
                    OUTl[ro + tx + 16*j] = f2bf(v - bf2f(hh));
                }
            }
        }
    }
}

// ---------------------------------------------------------------------------
extern "C" void kernel_launch(void* const* d_in, const int* in_sizes, int n_in,
                              void* d_out, int out_size, void* d_ws, size_t ws_size,
                              hipStream_t stream)
{
    const float* x         = (const float*)d_in[0];
    const float* w_ih_l0   = (const float*)d_in[1];
    const float* w_hh_l0   = (const float*)d_in[2];
    const float* b_ih_l0   = (const float*)d_in[3];
    const float* b_hh_l0   = (const float*)d_in[4];
    const float* w_ih_l0r  = (const float*)d_in[5];
    const float* w_hh_l0r  = (const float*)d_in[6];
    const float* b_ih_l0r  = (const float*)d_in[7];
    const float* b_hh_l0r  = (const float*)d_in[8];
    const float* w_ih_l1   = (const float*)d_in[9];
    const float* w_hh_l1   = (const float*)d_in[10];
    const float* b_ih_l1   = (const float*)d_in[11];
    const float* b_hh_l1   = (const float*)d_in[12];
    const float* w_ih_l1r  = (const float*)d_in[13];
    const float* w_hh_l1r  = (const float*)d_in[14];
    const float* b_ih_l1r  = (const float*)d_in[15];
    const float* b_hh_l1r  = (const float*)d_in[16];
    const float* qkv_w_t   = (const float*)d_in[17];
    const float* qkv_b_t   = (const float*)d_in[18];
    const float* rpb_t     = (const float*)d_in[19];
    const float* proj_w_t  = (const float*)d_in[20];
    const float* proj_b_t  = (const float*)d_in[21];
    const float* qkv_w_f   = (const float*)d_in[22];
    const float* qkv_b_f   = (const float*)d_in[23];
    const float* rpb_f     = (const float*)d_in[24];
    const float* proj_w_f  = (const float*)d_in[25];
    const float* proj_b_f  = (const float*)d_in[26];

    // Workspace (floats from base), ~278 MB:
    //  [0 .. 46,137,344)           XI f32 [MROWS][512]; later QKV f32
    //                              [MROWS][384] at base + ATT hi/lo pair in
    //                              the tail (exactly fits).
    //  [46,137,344 .. 57,671,680)  H hi/lo pair   (overlaid by Xhi initially)
    //  [57,671,680 .. 69,206,016)  G hi/lo pair   (overlaid by Xlo initially)
    //  [69,206,016 .. 69,533,696)  WH | WL weight bf16 pairs
    float* ws = (float*)d_ws;
    float*          XI   = ws;
    float*          QKV  = ws;
    unsigned short* ATTh = (unsigned short*)(ws + (size_t)MROWS * 384);
    unsigned short* ATTl = ATTh + (size_t)MROWS * 128;
    unsigned short* Hh   = (unsigned short*)(ws + 46137344);
    unsigned short* Hl   = Hh + (size_t)MROWS * 128;
    unsigned short* Gh   = (unsigned short*)(ws + 57671680);
    unsigned short* Gl   = Gh + (size_t)MROWS * 128;
    unsigned short* Xh   = (unsigned short*)(ws + 46137344);  // overlay H+G
    unsigned short* Xl   = Xh + (size_t)MROWS * 256;
    unsigned short* WH   = (unsigned short*)(ws + 69206016);
    unsigned short* WL   = WH + 327680;

    const int BIG = 1 << 30;
    const dim3 blk(256);

    convert_w<<<dim3(320), blk, 0, stream>>>(w_ih_l0, w_ih_l0r, w_ih_l1, w_ih_l1r,
        qkv_w_t, proj_w_t, qkv_w_f, proj_w_f, WH, WL);
    transpose_x<<<dim3(352, 4, 4), blk, 0, stream>>>(x, Xh, Xl);
    // 1) layer-0 input projection
    gemm_bf16<0><<<dim3(2816), blk, 0, stream>>>(Xh, Xl,
        WH, WL, WH + 65536, WL + 65536,
        b_ih_l0, b_hh_l0, b_ih_l0r, b_hh_l0r,
        XI, nullptr, nullptr, 512, 256, 256, 4);
    // 2) layer-0 recurrence
    lstm_kernel<<<dim3(704), blk, 0, stream>>>(XI, w_hh_l0, w_hh_l0r, Hh, Hl);
    // 3) layer-1 input projection
    gemm_bf16<0><<<dim3(2816), blk, 0, stream>>>(Hh, Hl,
        WH + 131072, WL + 131072, WH + 163840, WL + 163840,
        b_ih_l1, b_hh_l1, b_ih_l1r, b_hh_l1r,
        XI, nullptr, nullptr, 512, 128, 256, 4);
    // 4) layer-1 recurrence
    lstm_kernel<<<dim3(704), blk, 0, stream>>>(XI, w_hh_l1, w_hh_l1r, Hh, Hl);
    // 5) QKV for NA over t
    gemm_bf16<0><<<dim3(2112), blk, 0, stream>>>(Hh, Hl,
        WH + 196608, WL + 196608, WH + 196608, WL + 196608,
        qkv_b_t, nullptr, qkv_b_t, nullptr,
        QKV, nullptr, nullptr, 384, 128, BIG, 3);
    // 6) NA over t (kernel=7)
    na_t_kernel<<<dim3(22528), blk, 0, stream>>>(QKV, rpb_t, ATTh, ATTl);
    // 7) proj_t -> G (bf16 pair out)
    gemm_bf16<1><<<dim3(704), blk, 0, stream>>>(ATTh, ATTl,
        WH + 245760, WL + 245760, WH + 245760, WL + 245760,
        proj_b_t, nullptr, proj_b_t, nullptr,
        nullptr, Gh, Gl, 128, 128, BIG, 1);
    // 8) QKV for NA over p
    gemm_bf16<0><<<dim3(2112), blk, 0, stream>>>(Gh, Gl,
        WH + 262144, WL + 262144, WH + 262144, WL + 262144,
        qkv_b_f, nullptr, qkv_b_f, nullptr,
        QKV, nullptr, nullptr, 384, 128, BIG, 3);
    // 9) NA over p (kernel=87)
    na_f_kernel<<<dim3(1024), blk, 0, stream>>>(QKV, rpb_f, ATTh, ATTl);
    // 10) proj_f -> final output
    gemm_bf16<0><<<dim3(704), blk, 0, stream>>>(ATTh, ATTl,
        WH + 311296, WL + 311296, WH + 311296, WL + 311296,
        proj_b_f, nullptr, proj_b_f, nullptr,
        (float*)d_out, nullptr, nullptr, 128, 128, BIG, 1);
}